// Round 1
// baseline (385.213 us; speedup 1.0000x reference)
//
#include <hip/hip_runtime.h>
#include <math.h>
#include <float.h>

#define NPIX 2304   // 48*48
#define NPAD 2500   // 50*50
#define DDIM 200    // 25 images * 8 channels

// ws layout in floats
#define OFF_QP    0u          // [2][200][2500]
#define OFF_KP    1000000u    // [2][200][2500]
#define OFF_NK    2000000u    // [2][2500]
#define OFF_INVNK 2005000u    // [2][2304]
#define OFF_PVAL  2009608u    // [2][48][4][48]
#define OFF_PIDX  2028040u    // int [2][48][4][48]
#define OFF_IDX   2046472u    // int [2][2304]
#define OFF_S     2051080u    // [2500][2500] per-batch (reused)

// ---------------- stage 1: q = W*x1, k = W*x2, zero-padded, d-major ----------------
__global__ __launch_bounds__(256) void k_qk(const float* __restrict__ x1,
                                            const float* __restrict__ x2,
                                            const float* __restrict__ W,
                                            float* __restrict__ qp,
                                            float* __restrict__ kp) {
    __shared__ float Ws[512];
    const int t = threadIdx.x;
    Ws[t] = W[t];
    Ws[t + 256] = W[t + 256];
    __syncthreads();
    const int img = blockIdx.x / 9;      // 0..49  (b*25 + a)
    const int chunk = blockIdx.x % 9;
    const int pix = chunk * 256 + t;     // 0..2303
    const int b = img / 25, a = img % 25;
    const int y = pix / 48, x = pix % 48;

    float q[8], k[8];
#pragma unroll
    for (int o = 0; o < 8; ++o) { q[o] = 0.f; k[o] = 0.f; }

    const float* p1 = x1 + (size_t)b * 64 * 57600 + a * 2304 + pix;
    const float* p2 = x2 + (size_t)b * 64 * 57600 + a * 2304 + pix;
    for (int c = 0; c < 64; ++c) {
        float v1 = p1[c * 57600];
        float v2 = p2[c * 57600];
#pragma unroll
        for (int o = 0; o < 8; ++o) {
            float w = Ws[o * 64 + c];
            q[o] = fmaf(w, v1, q[o]);
            k[o] = fmaf(w, v2, k[o]);
        }
    }
    const int p = (y + 1) * 50 + (x + 1);
    const size_t base = (size_t)b * 500000 + (size_t)(a * 8) * NPAD + p;
#pragma unroll
    for (int o = 0; o < 8; ++o) {
        qp[base + o * NPAD] = q[o];
        kp[base + o * NPAD] = k[o];
    }
}

// ---------------- per-position squared norms of k ----------------
__global__ void k_nk(const float* __restrict__ kp, float* __restrict__ nk) {
    int t = blockIdx.x * 256 + threadIdx.x;  // 0..4999
    if (t >= 2 * NPAD) return;
    int b = t / NPAD, p = t - b * NPAD;
    const float* src = kp + (size_t)b * 500000 + p;
    float s = 0.f;
    for (int d = 0; d < DDIM; ++d) { float v = src[d * NPAD]; s = fmaf(v, v, s); }
    nk[t] = s;
}

__global__ void k_invnk(const float* __restrict__ nk, float* __restrict__ invNk) {
    int t = blockIdx.x * 256 + threadIdx.x;  // 0..4607
    if (t >= 2 * NPIX) return;
    int b = t / NPIX, m = t - b * NPIX;
    int my = m / 48, mx = m % 48;
    const float* nb = nk + b * NPAD;
    float s = 0.f;
#pragma unroll
    for (int i = 0; i < 3; ++i)
#pragma unroll
        for (int j = 0; j < 3; ++j)
            s += nb[(my + i) * 50 + mx + j];
    invNk[t] = 1.0f / fmaxf(sqrtf(s), 1e-12f);
}

// ---------------- stage 2a: S = A^T B, A,B = [200][2500], fp32 tiled GEMM ----------------
__global__ __launch_bounds__(256) void k_sgemm(const float* __restrict__ A,
                                               const float* __restrict__ B,
                                               float* __restrict__ S) {
    __shared__ __align__(16) float As[8][128];
    __shared__ __align__(16) float Bs[8][128];
    const int t = threadIdx.x;
    const int tx = t & 15, ty = t >> 4;
    const int p0 = blockIdx.y * 128, r0 = blockIdx.x * 128;
    const int ldd = t >> 5;           // 0..7
    const int ldp = (t & 31) << 2;    // 0..124 step 4
    const bool fullA = (p0 + 128 <= NPAD);
    const bool fullB = (r0 + 128 <= NPAD);

    float acc[8][8];
#pragma unroll
    for (int i = 0; i < 8; ++i)
#pragma unroll
        for (int j = 0; j < 8; ++j) acc[i][j] = 0.f;

    for (int dk = 0; dk < DDIM; dk += 8) {
        const float* arow = A + (size_t)(dk + ldd) * NPAD;
        const float* brow = B + (size_t)(dk + ldd) * NPAD;
        if (fullA) {
            *(float4*)&As[ldd][ldp] = *(const float4*)&arow[p0 + ldp];
        } else {
#pragma unroll
            for (int u = 0; u < 4; ++u) {
                int pp = p0 + ldp + u;
                As[ldd][ldp + u] = (pp < NPAD) ? arow[pp] : 0.f;
            }
        }
        if (fullB) {
            *(float4*)&Bs[ldd][ldp] = *(const float4*)&brow[r0 + ldp];
        } else {
#pragma unroll
            for (int u = 0; u < 4; ++u) {
                int rr = r0 + ldp + u;
                Bs[ldd][ldp + u] = (rr < NPAD) ? brow[rr] : 0.f;
            }
        }
        __syncthreads();
#pragma unroll
        for (int dd = 0; dd < 8; ++dd) {
            float af[8], bf[8];
            *(float4*)&af[0] = *(const float4*)&As[dd][ty * 8];
            *(float4*)&af[4] = *(const float4*)&As[dd][ty * 8 + 4];
            *(float4*)&bf[0] = *(const float4*)&Bs[dd][tx * 8];
            *(float4*)&bf[4] = *(const float4*)&Bs[dd][tx * 8 + 4];
#pragma unroll
            for (int i = 0; i < 8; ++i)
#pragma unroll
                for (int j = 0; j < 8; ++j)
                    acc[i][j] = fmaf(af[i], bf[j], acc[i][j]);
        }
        __syncthreads();
    }

#pragma unroll
    for (int i = 0; i < 8; ++i) {
        int p = p0 + ty * 8 + i;
        if (p < NPAD) {
            float* srow = S + (size_t)p * NPAD + r0 + tx * 8;
            if (fullB) {
                float4 v0 = { acc[i][0], acc[i][1], acc[i][2], acc[i][3] };
                float4 v1 = { acc[i][4], acc[i][5], acc[i][6], acc[i][7] };
                *(float4*)&srow[0] = v0;
                *(float4*)&srow[4] = v1;
            } else {
#pragma unroll
                for (int j = 0; j < 8; ++j)
                    if (r0 + tx * 8 + j < NPAD) srow[j] = acc[i][j];
            }
        }
    }
}

// ---------------- stage 2b: diagonal 3x3 box-sum + argmax over m ----------------
__global__ __launch_bounds__(384) void k_argmax(const float* __restrict__ S,
                                                const float* __restrict__ invNk,
                                                float* __restrict__ pval,
                                                int* __restrict__ pidx,
                                                int batch) {
    __shared__ float band[3][50][50];
    const int t = threadIdx.x;
    const int ly = blockIdx.x;     // 0..47
    const int chunk = blockIdx.y;  // 0..3
    const int lx = t >> 3;         // 0..47
    const int mc = t & 7;          // 0..7
    const float* inb = invNk + batch * NPIX;

    float best = -FLT_MAX;
    int bi = 0x7FFFFFFF;

    for (int my = chunk * 12; my < chunk * 12 + 12; ++my) {
        __syncthreads();
        for (int u = t; u < 7500; u += 384) {
            int i = u / 2500;
            int rem = u - i * 2500;
            int uu = rem / 50;
            int vv = rem - uu * 50;
            band[i][uu][vv] = S[(size_t)((ly + i) * 50 + uu) * NPAD + (my + i) * 50 + vv];
        }
        __syncthreads();
#pragma unroll
        for (int k = 0; k < 6; ++k) {
            int mx = mc + (k << 3);
            float s = 0.f;
#pragma unroll
            for (int i = 0; i < 3; ++i)
#pragma unroll
                for (int j = 0; j < 3; ++j)
                    s += band[i][lx + j][mx + j];
            int m = my * 48 + mx;
            float v = s * inb[m];
            if (v > best || (v == best && m < bi)) { best = v; bi = m; }
        }
    }
    // reduce across the 8 mc lanes (contiguous lanes within a wave)
#pragma unroll
    for (int off = 1; off < 8; off <<= 1) {
        float ov = __shfl_xor(best, off, 64);
        int oi = __shfl_xor(bi, off, 64);
        if (ov > best || (ov == best && oi < bi)) { best = ov; bi = oi; }
    }
    if (mc == 0) {
        int o = ((batch * 48 + ly) * 4 + chunk) * 48 + lx;
        pval[o] = best;
        pidx[o] = bi;
    }
}

__global__ void k_argred(const float* __restrict__ pval, const int* __restrict__ pidx,
                         int* __restrict__ idxout) {
    int t = blockIdx.x * 256 + threadIdx.x;
    if (t >= 2 * NPIX) return;
    int b = t / NPIX, l = t - b * NPIX;
    int ly = l / 48, lx = l % 48;
    float best = -FLT_MAX;
    int bi = 0x7FFFFFFF;
    for (int c = 0; c < 4; ++c) {
        int o = ((b * 48 + ly) * 4 + c) * 48 + lx;
        float v = pval[o];
        int i = pidx[o];
        if (v > best || (v == best && i < bi)) { best = v; bi = i; }
    }
    idxout[t] = bi;
}

// ---------------- stage 3: gather V patches + fold ----------------
__global__ __launch_bounds__(256) void k_out(const float* __restrict__ x3,
                                             const int* __restrict__ idx,
                                             float* __restrict__ out) {
    const int t = threadIdx.x;
    const int img = blockIdx.x / 9;
    const int chunk = blockIdx.x % 9;
    const int pix = chunk * 256 + t;
    const int b = img / 25, a = img % 25;
    const int y = pix / 48, x = pix % 48;

    int srcoff[9];
#pragma unroll
    for (int i = 0; i < 3; ++i) {
#pragma unroll
        for (int j = 0; j < 3; ++j) {
            int yq = y + 1 - i, xq = x + 1 - j;
            int so = -1;
            if (yq >= 0 && yq < 48 && xq >= 0 && xq < 48) {
                int m = idx[b * NPIX + yq * 48 + xq];
                int my = m / 48, mx = m % 48;
                int yy = my + i - 1, xx = mx + j - 1;
                if (yy >= 0 && yy < 48 && xx >= 0 && xx < 48)
                    so = yy * 48 + xx;
            }
            srcoff[i * 3 + j] = so;
        }
    }
    const float* src = x3 + (size_t)b * 64 * 57600 + a * 2304;
    float* dst = out + (size_t)b * 64 * 57600 + a * 2304 + pix;
    for (int c = 0; c < 64; ++c) {
        const float* sp = src + c * 57600;
        float acc = 0.f;
#pragma unroll
        for (int u = 0; u < 9; ++u)
            if (srcoff[u] >= 0) acc += sp[srcoff[u]];
        dst[c * 57600] = acc;
    }
}

extern "C" void kernel_launch(void* const* d_in, const int* in_sizes, int n_in,
                              void* d_out, int out_size, void* d_ws, size_t ws_size,
                              hipStream_t stream) {
    const float* x1 = (const float*)d_in[0];
    const float* x2 = (const float*)d_in[1];
    const float* x3 = (const float*)d_in[2];
    const float* W  = (const float*)d_in[3];
    float* ws = (float*)d_ws;

    float* qp    = ws + OFF_QP;
    float* kp    = ws + OFF_KP;
    float* nk    = ws + OFF_NK;
    float* invNk = ws + OFF_INVNK;
    float* pval  = ws + OFF_PVAL;
    int*   pidx  = (int*)(ws + OFF_PIDX);
    int*   idx   = (int*)(ws + OFF_IDX);
    float* S     = ws + OFF_S;
    float* out   = (float*)d_out;

    // zero-pad borders of qp/kp (contiguous 2M floats)
    hipMemsetAsync(qp, 0, 2000000 * sizeof(float), stream);

    k_qk<<<450, 256, 0, stream>>>(x1, x2, W, qp, kp);
    k_nk<<<(2 * NPAD + 255) / 256, 256, 0, stream>>>(kp, nk);
    k_invnk<<<(2 * NPIX + 255) / 256, 256, 0, stream>>>(nk, invNk);

    for (int b = 0; b < 2; ++b) {
        k_sgemm<<<dim3(20, 20), 256, 0, stream>>>(qp + (size_t)b * 500000,
                                                  kp + (size_t)b * 500000, S);
        k_argmax<<<dim3(48, 4), 384, 0, stream>>>(S, invNk, pval, pidx, b);
    }
    k_argred<<<(2 * NPIX + 255) / 256, 256, 0, stream>>>(pval, pidx, idx);
    k_out<<<450, 256, 0, stream>>>(x3, idx, out);
}

// Round 2
// 296.347 us; speedup vs baseline: 1.2999x; 1.2999x over previous
//
#include <hip/hip_runtime.h>
#include <math.h>
#include <float.h>

#define NPIX 2304   // 48*48
#define NPAD 2500   // 50*50
#define DDIM 200    // 25 images * 8 channels

// ws layout in floats
#define OFF_QP    0u          // [2][200][2500]
#define OFF_KP    1000000u    // [2][200][2500]
#define OFF_NK    2000000u    // [2][2500]
#define OFF_INVNK 2005000u    // [2][2304]
#define OFF_PVAL  2009608u    // [2][48][4][48]
#define OFF_PIDX  2028040u    // int [2][48][4][48]
#define OFF_IDX   2046472u    // int [2][2304]
#define OFF_S     2051080u    // [2500][2500] per-batch (reused)
#define OFF_SOFF  OFF_S       // int [2][9][2304] — reuses S region (S dead by then)

// ---------------- stage 1: q = W*x1, k = W*x2, zero-padded, d-major ----------------
__global__ __launch_bounds__(256) void k_qk(const float* __restrict__ x1,
                                            const float* __restrict__ x2,
                                            const float* __restrict__ W,
                                            float* __restrict__ qp,
                                            float* __restrict__ kp) {
    __shared__ float Ws[512];
    const int t = threadIdx.x;
    Ws[t] = W[t];
    Ws[t + 256] = W[t + 256];
    __syncthreads();
    const int img = blockIdx.x / 9;      // 0..49  (b*25 + a)
    const int chunk = blockIdx.x % 9;
    const int pix = chunk * 256 + t;     // 0..2303
    const int b = img / 25, a = img % 25;
    const int y = pix / 48, x = pix % 48;

    float q[8], k[8];
#pragma unroll
    for (int o = 0; o < 8; ++o) { q[o] = 0.f; k[o] = 0.f; }

    const float* p1 = x1 + (size_t)b * 64 * 57600 + a * 2304 + pix;
    const float* p2 = x2 + (size_t)b * 64 * 57600 + a * 2304 + pix;
    for (int c = 0; c < 64; ++c) {
        float v1 = p1[c * 57600];
        float v2 = p2[c * 57600];
#pragma unroll
        for (int o = 0; o < 8; ++o) {
            float w = Ws[o * 64 + c];
            q[o] = fmaf(w, v1, q[o]);
            k[o] = fmaf(w, v2, k[o]);
        }
    }
    const int p = (y + 1) * 50 + (x + 1);
    const size_t base = (size_t)b * 500000 + (size_t)(a * 8) * NPAD + p;
#pragma unroll
    for (int o = 0; o < 8; ++o) {
        qp[base + o * NPAD] = q[o];
        kp[base + o * NPAD] = k[o];
    }
}

// ---------------- per-position squared norms of k ----------------
__global__ void k_nk(const float* __restrict__ kp, float* __restrict__ nk) {
    int t = blockIdx.x * 256 + threadIdx.x;  // 0..4999
    if (t >= 2 * NPAD) return;
    int b = t / NPAD, p = t - b * NPAD;
    const float* src = kp + (size_t)b * 500000 + p;
    float s = 0.f;
    for (int d = 0; d < DDIM; ++d) { float v = src[d * NPAD]; s = fmaf(v, v, s); }
    nk[t] = s;
}

__global__ void k_invnk(const float* __restrict__ nk, float* __restrict__ invNk) {
    int t = blockIdx.x * 256 + threadIdx.x;  // 0..4607
    if (t >= 2 * NPIX) return;
    int b = t / NPIX, m = t - b * NPIX;
    int my = m / 48, mx = m % 48;
    const float* nb = nk + b * NPAD;
    float s = 0.f;
#pragma unroll
    for (int i = 0; i < 3; ++i)
#pragma unroll
        for (int j = 0; j < 3; ++j)
            s += nb[(my + i) * 50 + mx + j];
    invNk[t] = 1.0f / fmaxf(sqrtf(s), 1e-12f);
}

// ---------------- stage 2a: S = A^T B, A,B = [200][2500], fp32 tiled GEMM ----------------
__global__ __launch_bounds__(256) void k_sgemm(const float* __restrict__ A,
                                               const float* __restrict__ B,
                                               float* __restrict__ S) {
    __shared__ __align__(16) float As[8][128];
    __shared__ __align__(16) float Bs[8][128];
    const int t = threadIdx.x;
    const int tx = t & 15, ty = t >> 4;
    const int p0 = blockIdx.y * 128, r0 = blockIdx.x * 128;
    const int ldd = t >> 5;           // 0..7
    const int ldp = (t & 31) << 2;    // 0..124 step 4
    const bool fullA = (p0 + 128 <= NPAD);
    const bool fullB = (r0 + 128 <= NPAD);

    float acc[8][8];
#pragma unroll
    for (int i = 0; i < 8; ++i)
#pragma unroll
        for (int j = 0; j < 8; ++j) acc[i][j] = 0.f;

    for (int dk = 0; dk < DDIM; dk += 8) {
        const float* arow = A + (size_t)(dk + ldd) * NPAD;
        const float* brow = B + (size_t)(dk + ldd) * NPAD;
        if (fullA) {
            *(float4*)&As[ldd][ldp] = *(const float4*)&arow[p0 + ldp];
        } else {
#pragma unroll
            for (int u = 0; u < 4; ++u) {
                int pp = p0 + ldp + u;
                As[ldd][ldp + u] = (pp < NPAD) ? arow[pp] : 0.f;
            }
        }
        if (fullB) {
            *(float4*)&Bs[ldd][ldp] = *(const float4*)&brow[r0 + ldp];
        } else {
#pragma unroll
            for (int u = 0; u < 4; ++u) {
                int rr = r0 + ldp + u;
                Bs[ldd][ldp + u] = (rr < NPAD) ? brow[rr] : 0.f;
            }
        }
        __syncthreads();
#pragma unroll
        for (int dd = 0; dd < 8; ++dd) {
            float af[8], bf[8];
            *(float4*)&af[0] = *(const float4*)&As[dd][ty * 8];
            *(float4*)&af[4] = *(const float4*)&As[dd][ty * 8 + 4];
            *(float4*)&bf[0] = *(const float4*)&Bs[dd][tx * 8];
            *(float4*)&bf[4] = *(const float4*)&Bs[dd][tx * 8 + 4];
#pragma unroll
            for (int i = 0; i < 8; ++i)
#pragma unroll
                for (int j = 0; j < 8; ++j)
                    acc[i][j] = fmaf(af[i], bf[j], acc[i][j]);
        }
        __syncthreads();
    }

#pragma unroll
    for (int i = 0; i < 8; ++i) {
        int p = p0 + ty * 8 + i;
        if (p < NPAD) {
            float* srow = S + (size_t)p * NPAD + r0 + tx * 8;
            if (fullB) {
                float4 v0 = { acc[i][0], acc[i][1], acc[i][2], acc[i][3] };
                float4 v1 = { acc[i][4], acc[i][5], acc[i][6], acc[i][7] };
                *(float4*)&srow[0] = v0;
                *(float4*)&srow[4] = v1;
            } else {
#pragma unroll
                for (int j = 0; j < 8; ++j)
                    if (r0 + tx * 8 + j < NPAD) srow[j] = acc[i][j];
            }
        }
    }
}

// ---------------- stage 2b: diagonal 3x3 box-sum + argmax over m ----------------
__global__ __launch_bounds__(384) void k_argmax(const float* __restrict__ S,
                                                const float* __restrict__ invNk,
                                                float* __restrict__ pval,
                                                int* __restrict__ pidx,
                                                int batch) {
    __shared__ float band[3][50][50];
    const int t = threadIdx.x;
    const int ly = blockIdx.x;     // 0..47
    const int chunk = blockIdx.y;  // 0..3
    const int lx = t >> 3;         // 0..47
    const int mc = t & 7;          // 0..7
    const float* inb = invNk + batch * NPIX;

    float best = -FLT_MAX;
    int bi = 0x7FFFFFFF;

    for (int my = chunk * 12; my < chunk * 12 + 12; ++my) {
        __syncthreads();
        for (int u = t; u < 7500; u += 384) {
            int i = u / 2500;
            int rem = u - i * 2500;
            int uu = rem / 50;
            int vv = rem - uu * 50;
            band[i][uu][vv] = S[(size_t)((ly + i) * 50 + uu) * NPAD + (my + i) * 50 + vv];
        }
        __syncthreads();
#pragma unroll
        for (int k = 0; k < 6; ++k) {
            int mx = mc + (k << 3);
            float s = 0.f;
#pragma unroll
            for (int i = 0; i < 3; ++i)
#pragma unroll
                for (int j = 0; j < 3; ++j)
                    s += band[i][lx + j][mx + j];
            int m = my * 48 + mx;
            float v = s * inb[m];
            if (v > best || (v == best && m < bi)) { best = v; bi = m; }
        }
    }
    // reduce across the 8 mc lanes (contiguous lanes within a wave)
#pragma unroll
    for (int off = 1; off < 8; off <<= 1) {
        float ov = __shfl_xor(best, off, 64);
        int oi = __shfl_xor(bi, off, 64);
        if (ov > best || (ov == best && oi < bi)) { best = ov; bi = oi; }
    }
    if (mc == 0) {
        int o = ((batch * 48 + ly) * 4 + chunk) * 48 + lx;
        pval[o] = best;
        pidx[o] = bi;
    }
}

__global__ void k_argred(const float* __restrict__ pval, const int* __restrict__ pidx,
                         int* __restrict__ idxout) {
    int t = blockIdx.x * 256 + threadIdx.x;
    if (t >= 2 * NPIX) return;
    int b = t / NPIX, l = t - b * NPIX;
    int ly = l / 48, lx = l % 48;
    float best = -FLT_MAX;
    int bi = 0x7FFFFFFF;
    for (int c = 0; c < 4; ++c) {
        int o = ((b * 48 + ly) * 4 + c) * 48 + lx;
        float v = pval[o];
        int i = pidx[o];
        if (v > best || (v == best && i < bi)) { best = v; bi = i; }
    }
    idxout[t] = bi;
}

// ---------------- stage 3a: per-(b,pixel) 9 source offsets (tap-major layout) --------
__global__ void k_soff(const int* __restrict__ idx, int* __restrict__ soff) {
    int t = blockIdx.x * 256 + threadIdx.x;
    if (t >= 2 * NPIX) return;
    int b = t / NPIX, pix = t - b * NPIX;
    int y = pix / 48, x = pix % 48;
#pragma unroll
    for (int i = 0; i < 3; ++i) {
#pragma unroll
        for (int j = 0; j < 3; ++j) {
            int u = i * 3 + j;
            int yq = y + 1 - i, xq = x + 1 - j;
            int so = -1;
            if (yq >= 0 && yq < 48 && xq >= 0 && xq < 48) {
                int m = idx[b * NPIX + yq * 48 + xq];
                int my = m / 48, mx = m % 48;
                int yy = my + i - 1, xx = mx + j - 1;
                if (yy >= 0 && yy < 48 && xx >= 0 && xx < 48) so = yy * 48 + xx;
            }
            soff[(b * 9 + u) * NPIX + pix] = so;
        }
    }
}

// ---------------- stage 3b: gather + fold via LDS-staged plane ----------------
#define CPB 4  // channels per block
__global__ __launch_bounds__(256) void k_out2(const float* __restrict__ x3,
                                              const int* __restrict__ soff,
                                              float* __restrict__ out) {
    __shared__ __align__(16) float plane[NPIX];
    const int t = threadIdx.x;
    const int img = blockIdx.x;          // 0..49 (b*25 + a)
    const int b = img / 25, a = img % 25;
    const int c0 = blockIdx.y * CPB;

    // per-thread source offsets for its 9 pixels (pix = k*256 + t)
    int po[9][9];
#pragma unroll
    for (int u = 0; u < 9; ++u) {
        const int* sb = soff + (b * 9 + u) * NPIX;
#pragma unroll
        for (int k = 0; k < 9; ++k)
            po[k][u] = sb[k * 256 + t];
    }

    const size_t pbase = (size_t)b * 64 * 57600 + (size_t)a * 2304 + (size_t)c0 * 57600;
    const float* gsrc = x3 + pbase;
    float* gdst = out + pbase;

    // preload channel 0 plane
    float4 r0, r1, r2;
    {
        const float4* g = (const float4*)gsrc;
        r0 = g[t]; r1 = g[t + 256];
        if (t < 64) r2 = g[t + 512];
    }
    float4* pl4 = (float4*)plane;
    pl4[t] = r0; pl4[t + 256] = r1;
    if (t < 64) pl4[t + 512] = r2;
    __syncthreads();

    for (int c = 0; c < CPB; ++c) {
        // prefetch next channel into regs (overlaps with gather below)
        if (c + 1 < CPB) {
            const float4* g = (const float4*)(gsrc + (size_t)(c + 1) * 57600);
            r0 = g[t]; r1 = g[t + 256];
            if (t < 64) r2 = g[t + 512];
        }
        float* dst = gdst + (size_t)c * 57600;
#pragma unroll
        for (int k = 0; k < 9; ++k) {
            float acc = 0.f;
#pragma unroll
            for (int u = 0; u < 9; ++u) {
                int off = po[k][u];
                int ao = off < 0 ? 0 : off;
                float v = plane[ao];
                acc += (off < 0) ? 0.f : v;
            }
            dst[k * 256 + t] = acc;
        }
        __syncthreads();
        if (c + 1 < CPB) {
            pl4[t] = r0; pl4[t + 256] = r1;
            if (t < 64) pl4[t + 512] = r2;
        }
        __syncthreads();
    }
}

extern "C" void kernel_launch(void* const* d_in, const int* in_sizes, int n_in,
                              void* d_out, int out_size, void* d_ws, size_t ws_size,
                              hipStream_t stream) {
    const float* x1 = (const float*)d_in[0];
    const float* x2 = (const float*)d_in[1];
    const float* x3 = (const float*)d_in[2];
    const float* W  = (const float*)d_in[3];
    float* ws = (float*)d_ws;

    float* qp    = ws + OFF_QP;
    float* kp    = ws + OFF_KP;
    float* nk    = ws + OFF_NK;
    float* invNk = ws + OFF_INVNK;
    float* pval  = ws + OFF_PVAL;
    int*   pidx  = (int*)(ws + OFF_PIDX);
    int*   idx   = (int*)(ws + OFF_IDX);
    float* S     = ws + OFF_S;
    int*   soff  = (int*)(ws + OFF_SOFF);   // aliases S; S is dead by k_soff
    float* out   = (float*)d_out;

    // zero-pad borders of qp/kp (contiguous 2M floats)
    hipMemsetAsync(qp, 0, 2000000 * sizeof(float), stream);

    k_qk<<<450, 256, 0, stream>>>(x1, x2, W, qp, kp);
    k_nk<<<(2 * NPAD + 255) / 256, 256, 0, stream>>>(kp, nk);
    k_invnk<<<(2 * NPIX + 255) / 256, 256, 0, stream>>>(nk, invNk);

    for (int b = 0; b < 2; ++b) {
        k_sgemm<<<dim3(20, 20), 256, 0, stream>>>(qp + (size_t)b * 500000,
                                                  kp + (size_t)b * 500000, S);
        k_argmax<<<dim3(48, 4), 384, 0, stream>>>(S, invNk, pval, pidx, b);
    }
    k_argred<<<(2 * NPIX + 255) / 256, 256, 0, stream>>>(pval, pidx, idx);
    k_soff<<<(2 * NPIX + 255) / 256, 256, 0, stream>>>(idx, soff);
    k_out2<<<dim3(50, 16), 256, 0, stream>>>(x3, soff, out);
}

// Round 3
// 224.316 us; speedup vs baseline: 1.7173x; 1.3211x over previous
//
#include <hip/hip_runtime.h>
#include <math.h>
#include <float.h>

#define NPIX 2304   // 48*48
#define NPAD 2500   // 50*50
#define DDIM 200    // 25 images * 8 channels

// ws layout in floats
#define OFF_QP    0u          // [2][200][2500]
#define OFF_KP    1000000u    // [2][200][2500]
#define OFF_NK    2000000u    // [2][2500]
#define OFF_INVNK 2005000u    // [2][2304]
#define OFF_PVAL  2009608u    // [2][48][2304]  per-(my) partial best
#define OFF_PIDX  2230792u    // int [2][48][2304]
#define OFF_IDX   2451976u    // int [2][2304]
#define OFF_S     2456584u    // [2500][2500] per-batch (reused)
#define OFF_SOFF  OFF_S       // int [2][9][2304] — reuses S region (S dead by then)

// ---------------- stage 1: q = W*x1, k = W*x2, zero-padded, d-major ----------------
__global__ __launch_bounds__(256) void k_qk(const float* __restrict__ x1,
                                            const float* __restrict__ x2,
                                            const float* __restrict__ W,
                                            float* __restrict__ qp,
                                            float* __restrict__ kp) {
    __shared__ float Ws[512];
    const int t = threadIdx.x;
    Ws[t] = W[t];
    Ws[t + 256] = W[t + 256];
    __syncthreads();
    const int img = blockIdx.x / 9;      // 0..49  (b*25 + a)
    const int chunk = blockIdx.x % 9;
    const int pix = chunk * 256 + t;     // 0..2303
    const int b = img / 25, a = img % 25;
    const int y = pix / 48, x = pix % 48;

    float q[8], k[8];
#pragma unroll
    for (int o = 0; o < 8; ++o) { q[o] = 0.f; k[o] = 0.f; }

    const float* p1 = x1 + (size_t)b * 64 * 57600 + a * 2304 + pix;
    const float* p2 = x2 + (size_t)b * 64 * 57600 + a * 2304 + pix;
    for (int c = 0; c < 64; ++c) {
        float v1 = p1[c * 57600];
        float v2 = p2[c * 57600];
#pragma unroll
        for (int o = 0; o < 8; ++o) {
            float w = Ws[o * 64 + c];
            q[o] = fmaf(w, v1, q[o]);
            k[o] = fmaf(w, v2, k[o]);
        }
    }
    const int p = (y + 1) * 50 + (x + 1);
    const size_t base = (size_t)b * 500000 + (size_t)(a * 8) * NPAD + p;
#pragma unroll
    for (int o = 0; o < 8; ++o) {
        qp[base + o * NPAD] = q[o];
        kp[base + o * NPAD] = k[o];
    }
}

// ---------------- per-position squared norms of k ----------------
__global__ void k_nk(const float* __restrict__ kp, float* __restrict__ nk) {
    int t = blockIdx.x * 256 + threadIdx.x;  // 0..4999
    if (t >= 2 * NPAD) return;
    int b = t / NPAD, p = t - b * NPAD;
    const float* src = kp + (size_t)b * 500000 + p;
    float s = 0.f;
    for (int d = 0; d < DDIM; ++d) { float v = src[d * NPAD]; s = fmaf(v, v, s); }
    nk[t] = s;
}

__global__ void k_invnk(const float* __restrict__ nk, float* __restrict__ invNk) {
    int t = blockIdx.x * 256 + threadIdx.x;  // 0..4607
    if (t >= 2 * NPIX) return;
    int b = t / NPIX, m = t - b * NPIX;
    int my = m / 48, mx = m % 48;
    const float* nb = nk + b * NPAD;
    float s = 0.f;
#pragma unroll
    for (int i = 0; i < 3; ++i)
#pragma unroll
        for (int j = 0; j < 3; ++j)
            s += nb[(my + i) * 50 + mx + j];
    invNk[t] = 1.0f / fmaxf(sqrtf(s), 1e-12f);
}

// ---------------- stage 2a: S = A^T B, A,B = [200][2500], fp32 tiled GEMM ----------------
__global__ __launch_bounds__(256) void k_sgemm(const float* __restrict__ A,
                                               const float* __restrict__ B,
                                               float* __restrict__ S) {
    __shared__ __align__(16) float As[8][128];
    __shared__ __align__(16) float Bs[8][128];
    const int t = threadIdx.x;
    const int tx = t & 15, ty = t >> 4;
    const int p0 = blockIdx.y * 128, r0 = blockIdx.x * 128;
    const int ldd = t >> 5;           // 0..7
    const int ldp = (t & 31) << 2;    // 0..124 step 4
    const bool fullA = (p0 + 128 <= NPAD);
    const bool fullB = (r0 + 128 <= NPAD);

    float acc[8][8];
#pragma unroll
    for (int i = 0; i < 8; ++i)
#pragma unroll
        for (int j = 0; j < 8; ++j) acc[i][j] = 0.f;

    for (int dk = 0; dk < DDIM; dk += 8) {
        const float* arow = A + (size_t)(dk + ldd) * NPAD;
        const float* brow = B + (size_t)(dk + ldd) * NPAD;
        if (fullA) {
            *(float4*)&As[ldd][ldp] = *(const float4*)&arow[p0 + ldp];
        } else {
#pragma unroll
            for (int u = 0; u < 4; ++u) {
                int pp = p0 + ldp + u;
                As[ldd][ldp + u] = (pp < NPAD) ? arow[pp] : 0.f;
            }
        }
        if (fullB) {
            *(float4*)&Bs[ldd][ldp] = *(const float4*)&brow[r0 + ldp];
        } else {
#pragma unroll
            for (int u = 0; u < 4; ++u) {
                int rr = r0 + ldp + u;
                Bs[ldd][ldp + u] = (rr < NPAD) ? brow[rr] : 0.f;
            }
        }
        __syncthreads();
#pragma unroll
        for (int dd = 0; dd < 8; ++dd) {
            float af[8], bf[8];
            *(float4*)&af[0] = *(const float4*)&As[dd][ty * 8];
            *(float4*)&af[4] = *(const float4*)&As[dd][ty * 8 + 4];
            *(float4*)&bf[0] = *(const float4*)&Bs[dd][tx * 8];
            *(float4*)&bf[4] = *(const float4*)&Bs[dd][tx * 8 + 4];
#pragma unroll
            for (int i = 0; i < 8; ++i)
#pragma unroll
                for (int j = 0; j < 8; ++j)
                    acc[i][j] = fmaf(af[i], bf[j], acc[i][j]);
        }
        __syncthreads();
    }

#pragma unroll
    for (int i = 0; i < 8; ++i) {
        int p = p0 + ty * 8 + i;
        if (p < NPAD) {
            float* srow = S + (size_t)p * NPAD + r0 + tx * 8;
            if (fullB) {
                float4 v0 = { acc[i][0], acc[i][1], acc[i][2], acc[i][3] };
                float4 v1 = { acc[i][4], acc[i][5], acc[i][6], acc[i][7] };
                *(float4*)&srow[0] = v0;
                *(float4*)&srow[4] = v1;
            } else {
#pragma unroll
                for (int j = 0; j < 8; ++j)
                    if (r0 + tx * 8 + j < NPAD) srow[j] = acc[i][j];
            }
        }
    }
}

// ---------------- stage 2b: one block per (my, ly); 3x3 diagonal box-sum + partial argmax ----
__global__ __launch_bounds__(384) void k_argmax(const float* __restrict__ S,
                                                const float* __restrict__ invNk,
                                                float* __restrict__ pval,
                                                int* __restrict__ pidx,
                                                int batch) {
    __shared__ float band[3][50][50];
    const int t = threadIdx.x;
    const int my = blockIdx.x;     // 0..47
    const int ly = blockIdx.y;     // 0..47
    const int lx = t >> 3;         // 0..47
    const int mc = t & 7;          // 0..7

    for (int e = t; e < 7500; e += 384) {
        int i = e / 2500;
        int rem = e - i * 2500;
        int uu = rem / 50;
        int vv = rem - uu * 50;
        band[i][uu][vv] = S[(size_t)((ly + i) * 50 + uu) * NPAD + (my + i) * 50 + vv];
    }
    __syncthreads();

    const float* inb = invNk + batch * NPIX;
    float best = -FLT_MAX;
    int bi = 0x7FFFFFFF;

#pragma unroll
    for (int k = 0; k < 6; ++k) {
        int mx = mc + (k << 3);
        float s = 0.f;
#pragma unroll
        for (int i = 0; i < 3; ++i)
#pragma unroll
            for (int j = 0; j < 3; ++j)
                s += band[i][lx + j][mx + j];
        int m = my * 48 + mx;
        float v = s * inb[m];
        if (v > best || (v == best && m < bi)) { best = v; bi = m; }
    }
    // reduce across the 8 mc lanes (contiguous lanes within a wave)
#pragma unroll
    for (int off = 1; off < 8; off <<= 1) {
        float ov = __shfl_xor(best, off, 64);
        int oi = __shfl_xor(bi, off, 64);
        if (ov > best || (ov == best && oi < bi)) { best = ov; bi = oi; }
    }
    if (mc == 0) {
        int o = (batch * 48 + my) * NPIX + ly * 48 + lx;
        pval[o] = best;
        pidx[o] = bi;
    }
}

__global__ void k_argred(const float* __restrict__ pval, const int* __restrict__ pidx,
                         int* __restrict__ idxout) {
    int t = blockIdx.x * 256 + threadIdx.x;
    if (t >= 2 * NPIX) return;
    int b = t / NPIX, l = t - b * NPIX;
    float best = -FLT_MAX;
    int bi = 0x7FFFFFFF;
    for (int my = 0; my < 48; ++my) {
        int o = (b * 48 + my) * NPIX + l;
        float v = pval[o];
        int i = pidx[o];
        if (v > best || (v == best && i < bi)) { best = v; bi = i; }
    }
    idxout[t] = bi;
}

// ---------------- stage 3a: per-(b,pixel) 9 source offsets (tap-major layout) --------
__global__ void k_soff(const int* __restrict__ idx, int* __restrict__ soff) {
    int t = blockIdx.x * 256 + threadIdx.x;
    if (t >= 2 * NPIX) return;
    int b = t / NPIX, pix = t - b * NPIX;
    int y = pix / 48, x = pix % 48;
#pragma unroll
    for (int i = 0; i < 3; ++i) {
#pragma unroll
        for (int j = 0; j < 3; ++j) {
            int u = i * 3 + j;
            int yq = y + 1 - i, xq = x + 1 - j;
            int so = -1;
            if (yq >= 0 && yq < 48 && xq >= 0 && xq < 48) {
                int m = idx[b * NPIX + yq * 48 + xq];
                int my = m / 48, mx = m % 48;
                int yy = my + i - 1, xx = mx + j - 1;
                if (yy >= 0 && yy < 48 && xx >= 0 && xx < 48) so = yy * 48 + xx;
            }
            soff[(b * 9 + u) * NPIX + pix] = so;
        }
    }
}

// ---------------- stage 3b: gather + fold via LDS-staged plane ----------------
#define CPB 4  // channels per block
__global__ __launch_bounds__(256) void k_out2(const float* __restrict__ x3,
                                              const int* __restrict__ soff,
                                              float* __restrict__ out) {
    __shared__ __align__(16) float plane[NPIX];
    const int t = threadIdx.x;
    const int img = blockIdx.x;          // 0..49 (b*25 + a)
    const int b = img / 25, a = img % 25;
    const int c0 = blockIdx.y * CPB;

    // per-thread source offsets for its 9 pixels (pix = k*256 + t)
    int po[9][9];
#pragma unroll
    for (int u = 0; u < 9; ++u) {
        const int* sb = soff + (b * 9 + u) * NPIX;
#pragma unroll
        for (int k = 0; k < 9; ++k)
            po[k][u] = sb[k * 256 + t];
    }

    const size_t pbase = (size_t)b * 64 * 57600 + (size_t)a * 2304 + (size_t)c0 * 57600;
    const float* gsrc = x3 + pbase;
    float* gdst = out + pbase;

    // preload channel 0 plane
    float4 r0, r1, r2;
    {
        const float4* g = (const float4*)gsrc;
        r0 = g[t]; r1 = g[t + 256];
        if (t < 64) r2 = g[t + 512];
    }
    float4* pl4 = (float4*)plane;
    pl4[t] = r0; pl4[t + 256] = r1;
    if (t < 64) pl4[t + 512] = r2;
    __syncthreads();

    for (int c = 0; c < CPB; ++c) {
        // prefetch next channel into regs (overlaps with gather below)
        if (c + 1 < CPB) {
            const float4* g = (const float4*)(gsrc + (size_t)(c + 1) * 57600);
            r0 = g[t]; r1 = g[t + 256];
            if (t < 64) r2 = g[t + 512];
        }
        float* dst = gdst + (size_t)c * 57600;
#pragma unroll
        for (int k = 0; k < 9; ++k) {
            float acc = 0.f;
#pragma unroll
            for (int u = 0; u < 9; ++u) {
                int off = po[k][u];
                int ao = off < 0 ? 0 : off;
                float v = plane[ao];
                acc += (off < 0) ? 0.f : v;
            }
            dst[k * 256 + t] = acc;
        }
        __syncthreads();
        if (c + 1 < CPB) {
            pl4[t] = r0; pl4[t + 256] = r1;
            if (t < 64) pl4[t + 512] = r2;
        }
        __syncthreads();
    }
}

extern "C" void kernel_launch(void* const* d_in, const int* in_sizes, int n_in,
                              void* d_out, int out_size, void* d_ws, size_t ws_size,
                              hipStream_t stream) {
    const float* x1 = (const float*)d_in[0];
    const float* x2 = (const float*)d_in[1];
    const float* x3 = (const float*)d_in[2];
    const float* W  = (const float*)d_in[3];
    float* ws = (float*)d_ws;

    float* qp    = ws + OFF_QP;
    float* kp    = ws + OFF_KP;
    float* nk    = ws + OFF_NK;
    float* invNk = ws + OFF_INVNK;
    float* pval  = ws + OFF_PVAL;
    int*   pidx  = (int*)(ws + OFF_PIDX);
    int*   idx   = (int*)(ws + OFF_IDX);
    float* S     = ws + OFF_S;
    int*   soff  = (int*)(ws + OFF_SOFF);   // aliases S; S is dead by k_soff
    float* out   = (float*)d_out;

    // zero-pad borders of qp/kp (contiguous 2M floats)
    hipMemsetAsync(qp, 0, 2000000 * sizeof(float), stream);

    k_qk<<<450, 256, 0, stream>>>(x1, x2, W, qp, kp);
    k_nk<<<(2 * NPAD + 255) / 256, 256, 0, stream>>>(kp, nk);
    k_invnk<<<(2 * NPIX + 255) / 256, 256, 0, stream>>>(nk, invNk);

    for (int b = 0; b < 2; ++b) {
        k_sgemm<<<dim3(20, 20), 256, 0, stream>>>(qp + (size_t)b * 500000,
                                                  kp + (size_t)b * 500000, S);
        k_argmax<<<dim3(48, 48), 384, 0, stream>>>(S, invNk, pval, pidx, b);
    }
    k_argred<<<(2 * NPIX + 255) / 256, 256, 0, stream>>>(pval, pidx, idx);
    k_soff<<<(2 * NPIX + 255) / 256, 256, 0, stream>>>(idx, soff);
    k_out2<<<dim3(50, 16), 256, 0, stream>>>(x3, soff, out);
}

// Round 4
// 191.172 us; speedup vs baseline: 2.0150x; 1.1734x over previous
//
#include <hip/hip_runtime.h>
#include <math.h>
#include <float.h>

#define NPIX 2304   // 48*48
#define NPAD 2500   // 50*50
#define DDIM 200    // 25 images * 8 channels

// ws layout in floats
#define OFF_QP    0u          // [2][200][2500]
#define OFF_KP    1000000u    // [2][200][2500]
#define OFF_NK    2000000u    // [2][2500]
#define OFF_INVNK 2005000u    // [2][2304]
#define OFF_PVAL  2009608u    // [2][48][2304]  per-(my) partial best
#define OFF_PIDX  2230792u    // int [2][48][2304]
#define OFF_IDX   2451976u    // int [2][2304]
#define OFF_S     2456584u    // [z][2500][2500]  (1 or 2 buffers, ws_size permitting)
#define OFF_SOFF  OFF_S       // int [2][9][2304] — reuses S region (S dead by then)
#define SSTRIDE   6250000L

// ---------------- stage 1: q = W*x1, k = W*x2, zero-padded, d-major ----------------
__global__ __launch_bounds__(256) void k_qk(const float* __restrict__ x1,
                                            const float* __restrict__ x2,
                                            const float* __restrict__ W,
                                            float* __restrict__ qp,
                                            float* __restrict__ kp) {
    __shared__ float Ws[512];
    const int t = threadIdx.x;
    Ws[t] = W[t];
    Ws[t + 256] = W[t + 256];
    __syncthreads();
    const int img = blockIdx.x / 9;      // 0..49  (b*25 + a)
    const int chunk = blockIdx.x % 9;
    const int pix = chunk * 256 + t;     // 0..2303
    const int b = img / 25, a = img % 25;
    const int y = pix / 48, x = pix % 48;

    float q[8], k[8];
#pragma unroll
    for (int o = 0; o < 8; ++o) { q[o] = 0.f; k[o] = 0.f; }

    const float* p1 = x1 + (size_t)b * 64 * 57600 + a * 2304 + pix;
    const float* p2 = x2 + (size_t)b * 64 * 57600 + a * 2304 + pix;
    for (int c = 0; c < 64; ++c) {
        float v1 = p1[c * 57600];
        float v2 = p2[c * 57600];
#pragma unroll
        for (int o = 0; o < 8; ++o) {
            float w = Ws[o * 64 + c];
            q[o] = fmaf(w, v1, q[o]);
            k[o] = fmaf(w, v2, k[o]);
        }
    }
    const int p = (y + 1) * 50 + (x + 1);
    const size_t base = (size_t)b * 500000 + (size_t)(a * 8) * NPAD + p;
#pragma unroll
    for (int o = 0; o < 8; ++o) {
        qp[base + o * NPAD] = q[o];
        kp[base + o * NPAD] = k[o];
    }
}

// ---------------- per-position squared norms of k ----------------
__global__ void k_nk(const float* __restrict__ kp, float* __restrict__ nk) {
    int t = blockIdx.x * 256 + threadIdx.x;  // 0..4999
    if (t >= 2 * NPAD) return;
    int b = t / NPAD, p = t - b * NPAD;
    const float* src = kp + (size_t)b * 500000 + p;
    float s = 0.f;
    for (int d = 0; d < DDIM; ++d) { float v = src[d * NPAD]; s = fmaf(v, v, s); }
    nk[t] = s;
}

__global__ void k_invnk(const float* __restrict__ nk, float* __restrict__ invNk) {
    int t = blockIdx.x * 256 + threadIdx.x;  // 0..4607
    if (t >= 2 * NPIX) return;
    int b = t / NPIX, m = t - b * NPIX;
    int my = m / 48, mx = m % 48;
    const float* nb = nk + b * NPAD;
    float s = 0.f;
#pragma unroll
    for (int i = 0; i < 3; ++i)
#pragma unroll
        for (int j = 0; j < 3; ++j)
            s += nb[(my + i) * 50 + mx + j];
    invNk[t] = 1.0f / fmaxf(sqrtf(s), 1e-12f);
}

// ---------------- stage 2a: S = A^T B; 64(p) x 128(r) tiles, dbuf LDS, batch in z ----
__global__ __launch_bounds__(256, 4) void k_sgemm2(const float* __restrict__ qp,
                                                   const float* __restrict__ kp,
                                                   float* __restrict__ S,
                                                   long sStride, int bofs) {
    __shared__ __align__(16) float As[2][8][64];
    __shared__ __align__(16) float Bs[2][8][128];
    const int t = threadIdx.x;
    const int batch = bofs + blockIdx.z;
    const float* A = qp + (size_t)batch * 500000;
    const float* B = kp + (size_t)batch * 500000;
    float* Sb = S + (size_t)blockIdx.z * sStride;
    const int p0 = blockIdx.y * 64, r0 = blockIdx.x * 128;

    const int lr = t >> 5, lc = t & 31;  // loader: row (d) 0..7, lane-col 0..31
    // NOTE: loads deliberately unguarded — overruns land in adjacent defined ws
    // regions (max +59 floats past kp into nk); they only feed acc slots whose
    // stores are guarded below.
    const float* aptr = A + (size_t)lr * NPAD + p0 + lc * 2;
    const float* bptr = B + (size_t)lr * NPAD + r0 + lc * 4;

    float2 areg = *(const float2*)aptr;
    float4 breg = *(const float4*)bptr;
    *(float2*)&As[0][lr][lc * 2] = areg;
    *(float4*)&Bs[0][lr][lc * 4] = breg;
    __syncthreads();

    const int tx = t & 15, ty = t >> 4;
    float acc[4][8];
#pragma unroll
    for (int i = 0; i < 4; ++i)
#pragma unroll
        for (int j = 0; j < 8; ++j) acc[i][j] = 0.f;

    for (int it = 0; it < 25; ++it) {
        const int cur = it & 1;
        if (it + 1 < 25) {  // issue next-slice global loads (hide under fma burst)
            areg = *(const float2*)(aptr + (size_t)(it + 1) * 8 * NPAD);
            breg = *(const float4*)(bptr + (size_t)(it + 1) * 8 * NPAD);
        }
#pragma unroll
        for (int dd = 0; dd < 8; ++dd) {
            float a[4], b[8];
            *(float4*)&a[0] = *(const float4*)&As[cur][dd][ty * 4];
            *(float4*)&b[0] = *(const float4*)&Bs[cur][dd][tx * 4];
            *(float4*)&b[4] = *(const float4*)&Bs[cur][dd][64 + tx * 4];
#pragma unroll
            for (int i = 0; i < 4; ++i)
#pragma unroll
                for (int j = 0; j < 8; ++j)
                    acc[i][j] = fmaf(a[i], b[j], acc[i][j]);
        }
        if (it + 1 < 25) {
            __syncthreads();
            *(float2*)&As[cur ^ 1][lr][lc * 2] = areg;
            *(float4*)&Bs[cur ^ 1][lr][lc * 4] = breg;
            __syncthreads();
        }
    }

#pragma unroll
    for (int i = 0; i < 4; ++i) {
        const int p = p0 + ty * 4 + i;
        if (p < NPAD) {
            float* srow = Sb + (size_t)p * NPAD;
            const int c1 = r0 + tx * 4, c2 = c1 + 64;
            if (c2 + 3 < NPAD) {
                float4 v0 = { acc[i][0], acc[i][1], acc[i][2], acc[i][3] };
                float4 v1 = { acc[i][4], acc[i][5], acc[i][6], acc[i][7] };
                *(float4*)&srow[c1] = v0;
                *(float4*)&srow[c2] = v1;
            } else {
#pragma unroll
                for (int j = 0; j < 4; ++j) {
                    if (c1 + j < NPAD) srow[c1 + j] = acc[i][j];
                    if (c2 + j < NPAD) srow[c2 + j] = acc[i][4 + j];
                }
            }
        }
    }
}

// ---------------- stage 2b: one block per (my, ly, z); box-sum + partial argmax ----
__global__ __launch_bounds__(384) void k_argmax(const float* __restrict__ S,
                                                const float* __restrict__ invNk,
                                                float* __restrict__ pval,
                                                int* __restrict__ pidx,
                                                long sStride, int bofs) {
    __shared__ float band[3][50][50];
    const int t = threadIdx.x;
    const int my = blockIdx.x;     // 0..47
    const int ly = blockIdx.y;     // 0..47
    const int batch = bofs + blockIdx.z;
    const float* Sb = S + (size_t)blockIdx.z * sStride;
    const int lx = t >> 3;         // 0..47
    const int mc = t & 7;          // 0..7

    for (int e = t; e < 7500; e += 384) {
        int i = e / 2500;
        int rem = e - i * 2500;
        int uu = rem / 50;
        int vv = rem - uu * 50;
        band[i][uu][vv] = Sb[(size_t)((ly + i) * 50 + uu) * NPAD + (my + i) * 50 + vv];
    }
    __syncthreads();

    const float* inb = invNk + batch * NPIX;
    float best = -FLT_MAX;
    int bi = 0x7FFFFFFF;

#pragma unroll
    for (int k = 0; k < 6; ++k) {
        int mx = mc + (k << 3);
        float s = 0.f;
#pragma unroll
        for (int i = 0; i < 3; ++i)
#pragma unroll
            for (int j = 0; j < 3; ++j)
                s += band[i][lx + j][mx + j];
        int m = my * 48 + mx;
        float v = s * inb[m];
        if (v > best || (v == best && m < bi)) { best = v; bi = m; }
    }
#pragma unroll
    for (int off = 1; off < 8; off <<= 1) {
        float ov = __shfl_xor(best, off, 64);
        int oi = __shfl_xor(bi, off, 64);
        if (ov > best || (ov == best && oi < bi)) { best = ov; bi = oi; }
    }
    if (mc == 0) {
        int o = (batch * 48 + my) * NPIX + ly * 48 + lx;
        pval[o] = best;
        pidx[o] = bi;
    }
}

__global__ void k_argred(const float* __restrict__ pval, const int* __restrict__ pidx,
                         int* __restrict__ idxout) {
    int t = blockIdx.x * 256 + threadIdx.x;
    if (t >= 2 * NPIX) return;
    int b = t / NPIX, l = t - b * NPIX;
    float best = -FLT_MAX;
    int bi = 0x7FFFFFFF;
    for (int my = 0; my < 48; ++my) {
        int o = (b * 48 + my) * NPIX + l;
        float v = pval[o];
        int i = pidx[o];
        if (v > best || (v == best && i < bi)) { best = v; bi = i; }
    }
    idxout[t] = bi;
}

// ---------------- stage 3a: per-(b,pixel) 9 source offsets (tap-major layout) --------
__global__ void k_soff(const int* __restrict__ idx, int* __restrict__ soff) {
    int t = blockIdx.x * 256 + threadIdx.x;
    if (t >= 2 * NPIX) return;
    int b = t / NPIX, pix = t - b * NPIX;
    int y = pix / 48, x = pix % 48;
#pragma unroll
    for (int i = 0; i < 3; ++i) {
#pragma unroll
        for (int j = 0; j < 3; ++j) {
            int u = i * 3 + j;
            int yq = y + 1 - i, xq = x + 1 - j;
            int so = -1;
            if (yq >= 0 && yq < 48 && xq >= 0 && xq < 48) {
                int m = idx[b * NPIX + yq * 48 + xq];
                int my = m / 48, mx = m % 48;
                int yy = my + i - 1, xx = mx + j - 1;
                if (yy >= 0 && yy < 48 && xx >= 0 && xx < 48) so = yy * 48 + xx;
            }
            soff[(b * 9 + u) * NPIX + pix] = so;
        }
    }
}

// ---------------- stage 3b: gather + fold via LDS-staged plane ----------------
#define CPB 4  // channels per block
__global__ __launch_bounds__(256) void k_out2(const float* __restrict__ x3,
                                              const int* __restrict__ soff,
                                              float* __restrict__ out) {
    __shared__ __align__(16) float plane[NPIX];
    const int t = threadIdx.x;
    const int img = blockIdx.x;          // 0..49 (b*25 + a)
    const int b = img / 25, a = img % 25;
    const int c0 = blockIdx.y * CPB;

    int po[9][9];
#pragma unroll
    for (int u = 0; u < 9; ++u) {
        const int* sb = soff + (b * 9 + u) * NPIX;
#pragma unroll
        for (int k = 0; k < 9; ++k)
            po[k][u] = sb[k * 256 + t];
    }

    const size_t pbase = (size_t)b * 64 * 57600 + (size_t)a * 2304 + (size_t)c0 * 57600;
    const float* gsrc = x3 + pbase;
    float* gdst = out + pbase;

    float4 r0, r1, r2;
    {
        const float4* g = (const float4*)gsrc;
        r0 = g[t]; r1 = g[t + 256];
        if (t < 64) r2 = g[t + 512];
    }
    float4* pl4 = (float4*)plane;
    pl4[t] = r0; pl4[t + 256] = r1;
    if (t < 64) pl4[t + 512] = r2;
    __syncthreads();

    for (int c = 0; c < CPB; ++c) {
        if (c + 1 < CPB) {
            const float4* g = (const float4*)(gsrc + (size_t)(c + 1) * 57600);
            r0 = g[t]; r1 = g[t + 256];
            if (t < 64) r2 = g[t + 512];
        }
        float* dst = gdst + (size_t)c * 57600;
#pragma unroll
        for (int k = 0; k < 9; ++k) {
            float acc = 0.f;
#pragma unroll
            for (int u = 0; u < 9; ++u) {
                int off = po[k][u];
                int ao = off < 0 ? 0 : off;
                float v = plane[ao];
                acc += (off < 0) ? 0.f : v;
            }
            dst[k * 256 + t] = acc;
        }
        __syncthreads();
        if (c + 1 < CPB) {
            pl4[t] = r0; pl4[t + 256] = r1;
            if (t < 64) pl4[t + 512] = r2;
        }
        __syncthreads();
    }
}

extern "C" void kernel_launch(void* const* d_in, const int* in_sizes, int n_in,
                              void* d_out, int out_size, void* d_ws, size_t ws_size,
                              hipStream_t stream) {
    const float* x1 = (const float*)d_in[0];
    const float* x2 = (const float*)d_in[1];
    const float* x3 = (const float*)d_in[2];
    const float* W  = (const float*)d_in[3];
    float* ws = (float*)d_ws;

    float* qp    = ws + OFF_QP;
    float* kp    = ws + OFF_KP;
    float* nk    = ws + OFF_NK;
    float* invNk = ws + OFF_INVNK;
    float* pval  = ws + OFF_PVAL;
    int*   pidx  = (int*)(ws + OFF_PIDX);
    int*   idx   = (int*)(ws + OFF_IDX);
    float* S     = ws + OFF_S;
    int*   soff  = (int*)(ws + OFF_SOFF);   // aliases S; S is dead by k_soff
    float* out   = (float*)d_out;

    const bool bigS = ws_size >= (size_t)(OFF_S + 2u * (unsigned)SSTRIDE) * 4u;

    // zero-pad borders of qp/kp (contiguous 2M floats)
    hipMemsetAsync(qp, 0, 2000000 * sizeof(float), stream);

    k_qk<<<450, 256, 0, stream>>>(x1, x2, W, qp, kp);
    k_nk<<<(2 * NPAD + 255) / 256, 256, 0, stream>>>(kp, nk);
    k_invnk<<<(2 * NPIX + 255) / 256, 256, 0, stream>>>(nk, invNk);

    if (bigS) {
        k_sgemm2<<<dim3(20, 40, 2), 256, 0, stream>>>(qp, kp, S, SSTRIDE, 0);
        k_argmax<<<dim3(48, 48, 2), 384, 0, stream>>>(S, invNk, pval, pidx, SSTRIDE, 0);
    } else {
        for (int b = 0; b < 2; ++b) {
            k_sgemm2<<<dim3(20, 40, 1), 256, 0, stream>>>(qp, kp, S, 0L, b);
            k_argmax<<<dim3(48, 48, 1), 384, 0, stream>>>(S, invNk, pval, pidx, 0L, b);
        }
    }
    k_argred<<<(2 * NPIX + 255) / 256, 256, 0, stream>>>(pval, pidx, idx);
    k_soff<<<(2 * NPIX + 255) / 256, 256, 0, stream>>>(idx, soff);
    k_out2<<<dim3(50, 16), 256, 0, stream>>>(x3, soff, out);
}